// Round 9
// baseline (463.951 us; speedup 1.0000x reference)
//
#include <hip/hip_runtime.h>
#include <hip/hip_bf16.h>

// Problem constants
constexpr int N_ = 50000;
constexpr int D_ = 128;
constexpr int E_ = 800000;
constexpr int P_ = 9;
constexpr int L_ = 3;
constexpr float EPS_ = 1e-5f;

constexpr int TM = 64;    // rows per GEMM block
constexpr int CHUNK = 4096;                    // edges per hist/scatter block
constexpr int NBK = (E_ + CHUNK - 1) / CHUNK;  // 196 edge chunks
constexpr int NBUK = 196;                      // node buckets
constexpr int HHALF = 256 * NBK;               // 50176
constexpr int HTOT = 2 * HHALF;                // 100352 = 98 * 1024
constexpr int NSB = HTOT / 1024;               // 98 scan blocks
constexpr int MAT = L_ * P_;                   // 27 small matrices

typedef short bf16x8 __attribute__((ext_vector_type(8)));
typedef float f32x4 __attribute__((ext_vector_type(4)));

// async 16B global->LDS copy; lds base wave-uniform, lands at base + lane*16
#define GLD16(gp, lp)                                                        \
    __builtin_amdgcn_global_load_lds(                                        \
        (const __attribute__((address_space(1))) unsigned int*)(gp),         \
        (__attribute__((address_space(3))) unsigned int*)(lp), 16, 0, 0)

__device__ inline unsigned short f2bf(float f) {
    __hip_bfloat16 h = __float2bfloat16(f);
    return *reinterpret_cast<unsigned short*>(&h);
}
__device__ inline float bflo(unsigned u) { return __uint_as_float(u << 16); }
__device__ inline float bfhi(unsigned u) { return __uint_as_float(u & 0xffff0000u); }
__device__ inline float bf2f(unsigned short h) {
    return __uint_as_float((unsigned)h << 16);
}

// ---------------------------------------------------------------------------
// setup_nk: node polarity init + edge histograms (merged)
// ---------------------------------------------------------------------------

__global__ __launch_bounds__(256) void setup_nk(const int* __restrict__ ring,
                                                int* __restrict__ pol,
                                                int* __restrict__ bcnt,
                                                const int* __restrict__ ei,
                                                int* __restrict__ histG) {
    __shared__ int h[P_];
    __shared__ int hT[256], hS[256];
    int blk = blockIdx.x, tid = threadIdx.x;
    if (tid < P_) h[tid] = 0;
    hT[tid] = 0;
    hS[tid] = 0;
    __syncthreads();
    int n = blk * 256 + tid;
    if (n < N_) {
        int p = ring[n] % P_;
        pol[n] = p;
        atomicAdd(&h[p], 1);
    }
    int base = blk * CHUNK;
#pragma unroll
    for (int i = 0; i < CHUNK / 256; ++i) {
        int e = base + tid + i * 256;
        if (e < E_) {
            atomicAdd(&hS[ei[e] >> 8], 1);
            atomicAdd(&hT[ei[E_ + e] >> 8], 1);
        }
    }
    __syncthreads();
    if (tid < P_ && h[tid] > 0) atomicAdd(&bcnt[tid], h[tid]);
    histG[tid * NBK + blk] = hT[tid];
    histG[HHALF + tid * NBK + blk] = hS[tid];
}

// ---------------------------------------------------------------------------
// 3-phase exclusive scan of histG[HTOT]
// ---------------------------------------------------------------------------

__global__ __launch_bounds__(1024) void scanH1(int* __restrict__ a,
                                               int* __restrict__ blkSum) {
    __shared__ int wsum[16];
    int tid = threadIdx.x, lane = tid & 63, wid = tid >> 6;
    int idx = blockIdx.x * 1024 + tid;
    int v = a[idx];
    int inc = v;
#pragma unroll
    for (int o = 1; o < 64; o <<= 1) {
        int t = __shfl_up(inc, o, 64);
        if (lane >= o) inc += t;
    }
    if (lane == 63) wsum[wid] = inc;
    __syncthreads();
    if (tid < 16) {
        int s = wsum[tid];
#pragma unroll
        for (int o = 1; o < 16; o <<= 1) {
            int t = __shfl_up(s, o, 64);
            if (tid >= o) s += t;
        }
        wsum[tid] = s;
    }
    __syncthreads();
    int wexcl = (wid == 0) ? 0 : wsum[wid - 1];
    a[idx] = wexcl + inc - v;
    if (tid == 1023) blkSum[blockIdx.x] = wsum[15];
}

__global__ void scanH2(const int* __restrict__ blkSum, int* __restrict__ blkOff,
                       int* __restrict__ offT, const int* __restrict__ bcnt,
                       int* __restrict__ boff, int* __restrict__ tileOff) {
    if (threadIdx.x != 0) return;
    int run = 0;
    for (int i = 0; i < NSB; ++i) {
        blkOff[i] = run;
        run += blkSum[i];
    }
    offT[N_] = E_;
    boff[0] = 0;
    tileOff[0] = 0;
    for (int p = 0; p < P_; ++p) {
        boff[p + 1] = boff[p] + bcnt[p];
        tileOff[p + 1] = tileOff[p] + (bcnt[p] + TM - 1) / TM;
    }
}

__global__ __launch_bounds__(1024) void scanH3(int* __restrict__ a,
                                               const int* __restrict__ blkOff) {
    int idx = blockIdx.x * 1024 + threadIdx.x;
    a[idx] += blkOff[blockIdx.x];
}

// ---------------------------------------------------------------------------
// scatter into tgt-buckets (packed) and src-buckets (low byte)
// ---------------------------------------------------------------------------

__global__ __launch_bounds__(256) void scatterTS(const int* __restrict__ ei,
                                                 const int* __restrict__ histG,
                                                 unsigned* __restrict__ bufT,
                                                 unsigned char* __restrict__ bufS8) {
    __shared__ int ldsT[256], ldsS[256];
    int blk = blockIdx.x, tid = threadIdx.x;
    ldsT[tid] = histG[tid * NBK + blk];
    ldsS[tid] = histG[HHALF + tid * NBK + blk] - E_;
    __syncthreads();
    int base = blk * CHUNK;
#pragma unroll
    for (int i = 0; i < CHUNK / 256; ++i) {
        int e = base + tid + i * 256;
        if (e < E_) {
            int s = ei[e], t = ei[E_ + e];
            int pT = atomicAdd(&ldsT[t >> 8], 1);
            bufT[pT] = ((unsigned)t << 16) | (unsigned)s;
            int pS = atomicAdd(&ldsS[s >> 8], 1);
            bufS8[pS] = (unsigned char)(s & 255);
        }
    }
}

// ---------------------------------------------------------------------------
// finalize3: finalizeT | finalizeS | bucket_fill (+perm) by blockIdx role
// ---------------------------------------------------------------------------

__global__ __launch_bounds__(256) void finalize3(
    const unsigned* __restrict__ bufT, const unsigned char* __restrict__ bufS8,
    const int* __restrict__ histG, int* __restrict__ offT,
    unsigned short* __restrict__ eSrc, float* __restrict__ dnorm,
    const int* __restrict__ pol, const int* __restrict__ boff,
    int* __restrict__ bcur, int* __restrict__ blist, int* __restrict__ perm) {
    __shared__ int s0[256];
    __shared__ int s1[256];
    int bb = blockIdx.x, tid = threadIdx.x;

    if (bb < NBUK) {
        int b = bb;
        int start = histG[b * NBK];
        int end = histG[(b + 1) * NBK];
        s0[tid] = 0;
        __syncthreads();
        for (int i = start + tid; i < end; i += 256)
            atomicAdd(&s0[(bufT[i] >> 16) & 255], 1);
        __syncthreads();
        if (tid < 64) {
            int b0 = 4 * tid;
            int v0 = s0[b0], v1 = s0[b0 + 1], v2 = s0[b0 + 2], v3 = s0[b0 + 3];
            int lsum = v0 + v1 + v2 + v3;
            int inc = lsum;
#pragma unroll
            for (int o = 1; o < 64; o <<= 1) {
                int t = __shfl_up(inc, o, 64);
                if (tid >= o) inc += t;
            }
            int excl = inc - lsum;
            s1[b0] = excl;
            s1[b0 + 1] = excl + v0;
            s1[b0 + 2] = excl + v0 + v1;
            s1[b0 + 3] = excl + v0 + v1 + v2;
        }
        __syncthreads();
        int node = (b << 8) + tid;
        if (node < N_) offT[node] = start + s1[tid];
        __syncthreads();
        for (int i = start + tid; i < end; i += 256) {
            unsigned pk = bufT[i];
            int pos = start + atomicAdd(&s1[(pk >> 16) & 255], 1);
            eSrc[pos] = (unsigned short)(pk & 0xFFFF);
        }
    } else if (bb < 2 * NBUK) {
        int b = bb - NBUK;
        int start = histG[HHALF + b * NBK] - E_;
        int end = histG[HHALF + (b + 1) * NBK] - E_;
        s0[tid] = 0;
        __syncthreads();
        for (int i = start + tid; i < end; i += 256) atomicAdd(&s0[bufS8[i]], 1);
        __syncthreads();
        int node = (b << 8) + tid;
        if (node < N_) {
            int dg = s0[tid];
            dnorm[node] = 1.f / (float)(dg > 1 ? dg : 1);
        }
    } else {
        int b = bb - 2 * NBUK;
        if (tid < P_) s0[tid] = 0;
        __syncthreads();
        int n = b * 256 + tid;
        int p = 0, loc = 0;
        bool act = (n < N_);
        if (act) {
            p = pol[n];
            loc = atomicAdd(&s0[p], 1);
        }
        __syncthreads();
        if (tid < P_ && s0[tid] > 0) s1[tid] = atomicAdd(&bcur[tid], s0[tid]);
        __syncthreads();
        if (act) {
            int pos = boff[p] + s1[p] + loc;
            blist[pos] = n;
            perm[n] = pos;
        }
    }
}

// ---------------------------------------------------------------------------
// prep_all: permuted x conversion | zero dummy row | dnorm permute |
// eSrc remap to permuted ids | prep_S | prep_W2 | prep_split
// ---------------------------------------------------------------------------

constexpr int GCONV = N_ * D_ / 4 / 256;       // 6250
constexpr int GDN = (N_ + 255) / 256;          // 196
constexpr int GER = (E_ + 255) / 256;          // 3125
constexpr int GS = L_ * P_ * D_ * D_ / 256;    // 1728
constexpr int GW2 = L_ * D_ * D_ / 256;        // 192
constexpr int GSPL = (MAT + 6) * 16384 / 256;  // 2112
constexpr int GPREP = GCONV + 1 + GDN + GER + GS + GW2 + GSPL;

__global__ __launch_bounds__(256) void prep_all(
    const float* __restrict__ x, const int* __restrict__ perm,
    const int* __restrict__ blist, unsigned short* __restrict__ xbP,
    float* __restrict__ xbufP, unsigned short* __restrict__ bufAb,
    const float* __restrict__ dnorm, float* __restrict__ dnormp,
    unsigned short* __restrict__ eSrc,
    const float* __restrict__ S, const float* __restrict__ dS,
    unsigned short* __restrict__ Sb,
    const float* __restrict__ W2, unsigned short* __restrict__ W2b,
    const float* __restrict__ R, const float* __restrict__ dR,
    const float* __restrict__ W1, const float* __restrict__ Wr,
    unsigned short* __restrict__ Arh, unsigned short* __restrict__ Arl,
    unsigned short* __restrict__ W1h, unsigned short* __restrict__ W1l,
    unsigned short* __restrict__ Wrth, unsigned short* __restrict__ Wrtl) {
    int b = blockIdx.x, tid = threadIdx.x;
    if (b < GCONV) {
        int i = b * 256 + tid;       // group of 4 floats
        int n = i >> 5, g4 = i & 31; // row n, float4-group g4
        int pr = perm[n];
        float4 v = ((const float4*)x)[i];
        ushort4 o;
        o.x = f2bf(v.x); o.y = f2bf(v.y); o.z = f2bf(v.z); o.w = f2bf(v.w);
        ((ushort4*)(xbP + (size_t)pr * D_))[g4] = o;
        ((float4*)(xbufP + (size_t)pr * D_))[g4] = v;
    } else if (b < GCONV + 1) {
        if (tid < 64) ((unsigned*)(bufAb + (size_t)N_ * D_))[tid] = 0;
    } else if (b < GCONV + 1 + GDN) {
        int i = (b - GCONV - 1) * 256 + tid;
        if (i < N_) dnormp[i] = dnorm[blist[i]];
    } else if (b < GCONV + 1 + GDN + GER) {
        int e = (b - GCONV - 1 - GDN) * 256 + tid;
        if (e < E_) eSrc[e] = (unsigned short)perm[eSrc[e]];
    } else if (b < GCONV + 1 + GDN + GER + GS) {
        int idx = (b - GCONV - 1 - GDN - GER) * 256 + tid;
        int base = idx / (D_ * D_);
        int rem = idx % (D_ * D_);
        int c = rem / D_, d = rem % D_;
        size_t in = (size_t)base * D_ * D_ + (size_t)d * D_ + c;
        Sb[idx] = f2bf(S[in] + dS[in]);
    } else if (b < GCONV + 1 + GDN + GER + GS + GW2) {
        int idx = (b - GCONV - 1 - GDN - GER - GS) * 256 + tid;
        W2b[idx] = f2bf(W2[idx]);
    } else {
        constexpr int SZ1 = MAT * 16384;
        constexpr int SZ2 = SZ1 + 3 * 16384;
        int idx = (b - GCONV - 1 - GDN - GER - GS - GW2) * 256 + tid;
        float v;
        unsigned short* oh;
        unsigned short* ol;
        int j;
        if (idx < SZ1) {
            v = R[idx] + dR[idx];
            oh = Arh; ol = Arl; j = idx;
        } else if (idx < SZ2) {
            j = idx - SZ1;
            v = W1[j];
            oh = W1h; ol = W1l;
        } else {
            j = idx - SZ2;
            int l = j >> 14, rem = j & 16383;
            int d = rem >> 7, i = rem & 127;
            v = Wr[(l << 14) + i * 128 + d];
            oh = Wrth; ol = Wrtl;
        }
        unsigned short h = f2bf(v);
        oh[j] = h;
        ol[j] = f2bf(v - bf2f(h));
    }
}

// ---------------------------------------------------------------------------
// Batched small MFMA GEMM (fp32-equivalent via 2-term bf16 split)
// ---------------------------------------------------------------------------

template <bool APM, bool BPM, bool OUT_SPLIT>
__global__ __launch_bounds__(256) void small_mfma(
    const unsigned short* __restrict__ Ah, const unsigned short* __restrict__ Al,
    const unsigned short* __restrict__ Bh, const unsigned short* __restrict__ Bl,
    unsigned short* __restrict__ Oh, unsigned short* __restrict__ Ol) {
    __shared__ unsigned short stg[(OUT_SPLIT ? 2 : 1) * 64 * 136];
    int tid = threadIdx.x, b = blockIdx.x;
    int mat = b >> 1, rb = b & 1;
    int l = mat / P_;
    size_t aoff = (size_t)(APM ? mat : l) * 16384 + (size_t)rb * 8192;
    size_t boff = (size_t)(BPM ? mat : l) * 16384;
    const unsigned short* ahp = Ah + aoff;
    const unsigned short* alp = Al + aoff;
    const unsigned short* bhp = Bh + boff;
    const unsigned short* blp = Bl + boff;

    int lane = tid & 63, wave = tid >> 6;
    int n = lane & 15, q = lane >> 4;
    int wr = wave * 16;

    f32x4 acc[8];
#pragma unroll
    for (int t = 0; t < 8; ++t) acc[t] = (f32x4){0.f, 0.f, 0.f, 0.f};

    int arow = (wr + n) * 128;
#pragma unroll
    for (int kc = 0; kc < 4; ++kc) {
        int ko = kc * 32 + q * 8;
        bf16x8 avh = *(const bf16x8*)(ahp + arow + ko);
        bf16x8 avl = *(const bf16x8*)(alp + arow + ko);
#pragma unroll
        for (int t = 0; t < 8; ++t) {
            int brow = (t * 16 + n) * 128;
            bf16x8 bvh = *(const bf16x8*)(bhp + brow + ko);
            bf16x8 bvl = *(const bf16x8*)(blp + brow + ko);
            acc[t] = __builtin_amdgcn_mfma_f32_16x16x32_bf16(avh, bvh, acc[t], 0, 0, 0);
            acc[t] = __builtin_amdgcn_mfma_f32_16x16x32_bf16(avh, bvl, acc[t], 0, 0, 0);
            acc[t] = __builtin_amdgcn_mfma_f32_16x16x32_bf16(avl, bvh, acc[t], 0, 0, 0);
        }
    }
#pragma unroll
    for (int t = 0; t < 8; ++t)
#pragma unroll
        for (int r = 0; r < 4; ++r) {
            int row = wr + q * 4 + r;
            float v = acc[t][r];
            unsigned short h = f2bf(v);
            stg[row * 136 + t * 16 + n] = h;
            if constexpr (OUT_SPLIT)
                stg[64 * 136 + row * 136 + t * 16 + n] = f2bf(v - bf2f(h));
        }
    __syncthreads();
    size_t obase = (size_t)mat * 16384 + (size_t)rb * 8192;
#pragma unroll
    for (int i = 0; i < 4; ++i) {
        int c = tid + i * 256;
        int r = c >> 4, off = c & 15;
        *(uint4*)(Oh + obase + r * 128 + off * 8) =
            *(const uint4*)(stg + r * 136 + off * 8);
        if constexpr (OUT_SPLIT)
            *(uint4*)(Ol + obase + r * 128 + off * 8) =
                *(const uint4*)(stg + 64 * 136 + r * 136 + off * 8);
    }
}

// ---------------------------------------------------------------------------
// CSR aggregation (eSrc already permuted); writes to permuted position
// ---------------------------------------------------------------------------

__device__ inline void accum_row(float* acc, uint4 r) {
    acc[0] += bflo(r.x); acc[1] += bfhi(r.x);
    acc[2] += bflo(r.y); acc[3] += bfhi(r.y);
    acc[4] += bflo(r.z); acc[5] += bfhi(r.z);
    acc[6] += bflo(r.w); acc[7] += bfhi(r.w);
}

__global__ __launch_bounds__(256) void aggregate_bf(const unsigned short* __restrict__ xt,
                                                    const int* __restrict__ offT,
                                                    const unsigned short* __restrict__ eSrc,
                                                    unsigned short* __restrict__ agg,
                                                    const int* __restrict__ perm) {
    int nd = blockIdx.x * 4 + (threadIdx.x >> 6);
    if (nd >= N_) return;
    int l = threadIdx.x & 63;
    int g = l >> 4, c16 = l & 15;
    int beg = offT[nd], end = offT[nd + 1];

    float acc[8];
#pragma unroll
    for (int k = 0; k < 8; ++k) acc[k] = 0.f;

    for (int base = beg; base < end; base += 64) {
        int cnt = min(64, end - base);
        int idxv = (l < cnt) ? (int)eSrc[base + l] : 0;
        int steps = (cnt + 3) >> 2;
        int j = 0;
        for (; j + 3 < steps; j += 4) {
            int e0 = 4 * j + g, e1 = e0 + 4, e2 = e0 + 8, e3 = e0 + 12;
            int i0 = __shfl(idxv, e0, 64);
            int i1 = __shfl(idxv, e1, 64);
            int i2 = __shfl(idxv, e2, 64);
            int i3 = __shfl(idxv, e3, 64);
            int r0 = (e0 < cnt) ? i0 : N_;
            int r1 = (e1 < cnt) ? i1 : N_;
            int r2 = (e2 < cnt) ? i2 : N_;
            int r3 = (e3 < cnt) ? i3 : N_;
            uint4 v0 = ((const uint4*)(xt + (size_t)r0 * D_))[c16];
            uint4 v1 = ((const uint4*)(xt + (size_t)r1 * D_))[c16];
            uint4 v2 = ((const uint4*)(xt + (size_t)r2 * D_))[c16];
            uint4 v3 = ((const uint4*)(xt + (size_t)r3 * D_))[c16];
            accum_row(acc, v0);
            accum_row(acc, v1);
            accum_row(acc, v2);
            accum_row(acc, v3);
        }
        for (; j < steps; ++j) {
            int e0 = 4 * j + g;
            int i0 = __shfl(idxv, e0, 64);
            int r0 = (e0 < cnt) ? i0 : N_;
            uint4 v0 = ((const uint4*)(xt + (size_t)r0 * D_))[c16];
            accum_row(acc, v0);
        }
    }
#pragma unroll
    for (int k = 0; k < 8; ++k) {
        acc[k] += __shfl_xor(acc[k], 16, 64);
        acc[k] += __shfl_xor(acc[k], 32, 64);
    }
    if (g == 0) {
        int pnd = perm[nd];
        uint4 o;
        o.x = (unsigned)f2bf(acc[0]) | ((unsigned)f2bf(acc[1]) << 16);
        o.y = (unsigned)f2bf(acc[2]) | ((unsigned)f2bf(acc[3]) << 16);
        o.z = (unsigned)f2bf(acc[4]) | ((unsigned)f2bf(acc[5]) << 16);
        o.w = (unsigned)f2bf(acc[6]) | ((unsigned)f2bf(acc[7]) << 16);
        ((uint4*)(agg + (size_t)pnd * D_))[c16] = o;
    }
}

// ---------------------------------------------------------------------------
// Barrier-free GEMM plumbing. Permuted layout: A rows contiguous. LDS holds
// only the A tile (swizzled: 16B chunk c of row r at c ^ (r&15)); each wave
// stages, reads, transposes, and stores ONLY its own 16 rows (DS in-order per
// wave => no __syncthreads needed). B fragments read directly from L2.
// ---------------------------------------------------------------------------

__device__ inline void stage_A_contig(const unsigned short* __restrict__ A,
                                      int rowbase, unsigned short* sA,
                                      int wave, int lane) {
    int rsub = lane >> 4, cl = lane & 15;
#pragma unroll
    for (int j = 0; j < 4; ++j) {
        int seg = wave * 4 + j;
        int rloc = seg * 4 + rsub;
        GLD16(A + (size_t)(rowbase + rloc) * D_ + ((cl ^ (rloc & 15)) << 3),
              sA + seg * 512);
    }
}

// gemm_xt0: xt_p = xb_p @ Sb[0][pol]
__global__ __launch_bounds__(256) void gemm_xt0(
    const unsigned short* __restrict__ A, const unsigned short* __restrict__ Bw,
    unsigned short* __restrict__ OutB, const int* __restrict__ boff,
    const int* __restrict__ tileOff) {
    __shared__ unsigned short sA[64 * 128];
    int tid = threadIdx.x, b = blockIdx.x;
    if (b >= tileOff[P_]) return;
    int pp = 0;
    while (pp < P_ - 1 && b >= tileOff[pp + 1]) ++pp;
    int tb = b - tileOff[pp];
    int cnt = boff[pp + 1] - boff[pp];
    int nrows = min(TM, cnt - tb * TM);
    int rowbase = boff[pp] + tb * TM;

    int lane = tid & 63, wave = tid >> 6;
    stage_A_contig(A, rowbase, sA, wave, lane);
    const unsigned short* Bp = Bw + (size_t)pp * D_ * D_;

    int n = lane & 15, q = lane >> 4, wr = wave * 16;
    __builtin_amdgcn_s_waitcnt(0);  // own async stages done (per-wave)

    f32x4 acc[8];
#pragma unroll
    for (int t = 0; t < 8; ++t) acc[t] = (f32x4){0.f, 0.f, 0.f, 0.f};
#pragma unroll
    for (int kc = 0; kc < 4; ++kc) {
        int cs = (((kc << 2) + q) ^ n) << 3;
        bf16x8 af = *(const bf16x8*)(sA + (wr + n) * 128 + cs);
        int ko = kc * 32 + q * 8;
#pragma unroll
        for (int t = 0; t < 8; ++t) {
            bf16x8 bv = *(const bf16x8*)(Bp + (t * 16 + n) * 128 + ko);
            acc[t] = __builtin_amdgcn_mfma_f32_16x16x32_bf16(af, bv, acc[t], 0, 0, 0);
        }
    }
    // transpose into own rows, then wave-local coalesced store
#pragma unroll
    for (int t = 0; t < 8; ++t)
#pragma unroll
        for (int r = 0; r < 4; ++r) {
            int rl = q * 4 + r;
            int c = (t * 16 + n) >> 3;
            sA[(wr + rl) * 128 + ((c ^ rl) << 3) + (n & 7)] = f2bf(acc[t][r]);
        }
    int rl2 = lane >> 2, cb = lane & 3;
    if (rl2 < nrows - wr) {
#pragma unroll
        for (int i = 0; i < 4; ++i) {
            int c = i * 4 + cb;
            uint4 v = *(const uint4*)(sA + (wr + rl2) * 128 + ((c ^ rl2) << 3));
            *(uint4*)(OutB + (size_t)(rowbase + wr + rl2) * D_ + (c << 3)) = v;
        }
    }
}

// fused_layer: GEMM1(agg@Dm)+LN+relu -> GEMM2(h@W2^T)+res+LN ->
// [GEMM3(x'@Sn) unless LAST]. Fully wave-autonomous, zero barriers.
template <bool LAST>
__global__ __launch_bounds__(256) void fused_layer(
    const unsigned short* __restrict__ agg, const unsigned short* __restrict__ DmAll,
    const unsigned short* __restrict__ W2b, const unsigned short* __restrict__ SnAll,
    const int* __restrict__ boff, const int* __restrict__ tileOff,
    const int* __restrict__ blist, const float* __restrict__ dnormp,
    const float* __restrict__ b1v, const float* __restrict__ g1v,
    const float* __restrict__ e1v, const float* __restrict__ b2v,
    const float* __restrict__ g2v, const float* __restrict__ e2v,
    const float* __restrict__ rs_ptr, const float* __restrict__ xresP,
    const float* __restrict__ x0, float* __restrict__ OutF,
    unsigned short* __restrict__ OutXt) {
    __shared__ unsigned short sA[64 * 128];
    int tid = threadIdx.x, b = blockIdx.x;
    if (b >= tileOff[P_]) return;
    int pp = 0;
    while (pp < P_ - 1 && b >= tileOff[pp + 1]) ++pp;
    int tb = b - tileOff[pp];
    int cnt = boff[pp + 1] - boff[pp];
    int nrows = min(TM, cnt - tb * TM);
    int rowbase = boff[pp] + tb * TM;

    int lane = tid & 63, wave = tid >> 6;
    stage_A_contig(agg, rowbase, sA, wave, lane);

    int n = lane & 15, q = lane >> 4, wr = wave * 16;
    const unsigned short* Bp = DmAll + (size_t)pp * D_ * D_;
    float dn4[4];
#pragma unroll
    for (int r = 0; r < 4; ++r) dn4[r] = dnormp[rowbase + wr + q * 4 + r];

    __builtin_amdgcn_s_waitcnt(0);  // own async stages done (per-wave)

    // ---- GEMM1: agg @ Dm ----
    f32x4 acc[8];
#pragma unroll
    for (int t = 0; t < 8; ++t) acc[t] = (f32x4){0.f, 0.f, 0.f, 0.f};
#pragma unroll
    for (int kc = 0; kc < 4; ++kc) {
        int cs = (((kc << 2) + q) ^ n) << 3;
        bf16x8 af = *(const bf16x8*)(sA + (wr + n) * 128 + cs);
        int ko = kc * 32 + q * 8;
#pragma unroll
        for (int t = 0; t < 8; ++t) {
            bf16x8 bv = *(const bf16x8*)(Bp + (t * 16 + n) * 128 + ko);
            acc[t] = __builtin_amdgcn_mfma_f32_16x16x32_bf16(af, bv, acc[t], 0, 0, 0);
        }
    }

    // ---- LN1 + relu -> h ----
    {
        float rs1[4] = {0, 0, 0, 0}, rs2[4] = {0, 0, 0, 0};
#pragma unroll
        for (int t = 0; t < 8; ++t) {
            int col = t * 16 + n;
            float bia = b1v[col];
#pragma unroll
            for (int r = 0; r < 4; ++r) {
                float v = dn4[r] * acc[t][r] + bia;
                acc[t][r] = v;
                rs1[r] += v;
                rs2[r] += v * v;
            }
        }
#pragma unroll
        for (int mk = 1; mk < 16; mk <<= 1)
#pragma unroll
            for (int r = 0; r < 4; ++r) {
                rs1[r] += __shfl_xor(rs1[r], mk, 64);
                rs2[r] += __shfl_xor(rs2[r], mk, 64);
            }
        float mr[4], rv[4];
#pragma unroll
        for (int r = 0; r < 4; ++r) {
            float mm = rs1[r] * (1.f / 128.f);
            mr[r] = mm;
            rv[r] = rsqrtf(rs2[r] * (1.f / 128.f) - mm * mm + EPS_);
        }
#pragma unroll
        for (int t = 0; t < 8; ++t) {
            int col = t * 16 + n;
            float gg = g1v[col], bbv = e1v[col];
#pragma unroll
            for (int r = 0; r < 4; ++r)
                acc[t][r] = fmaxf((acc[t][r] - mr[r]) * rv[r] * gg + bbv, 0.f);
        }
    }

    // transpose h into own sA rows (wave-local; DS in-order per wave)
#pragma unroll
    for (int t = 0; t < 8; ++t)
#pragma unroll
        for (int r = 0; r < 4; ++r) {
            int rl = q * 4 + r;
            int c = (t * 16 + n) >> 3;
            sA[(wr + rl) * 128 + ((c ^ rl) << 3) + (n & 7)] = f2bf(acc[t][r]);
        }

    // ---- GEMM2: h @ W2^T ----
#pragma unroll
    for (int t = 0; t < 8; ++t) acc[t] = (f32x4){0.f, 0.f, 0.f, 0.f};
#pragma unroll
    for (int kc = 0; kc < 4; ++kc) {
        int cs = (((kc << 2) + q) ^ n) << 3;
        bf16x8 af = *(const bf16x8*)(sA + (wr + n) * 128 + cs);
        int ko = kc * 32 + q * 8;
#pragma unroll
        for (int t = 0; t < 8; ++t) {
            bf16x8 bv = *(const bf16x8*)(W2b + (t * 16 + n) * 128 + ko);
            acc[t] = __builtin_amdgcn_mfma_f32_16x16x32_bf16(af, bv, acc[t], 0, 0, 0);
        }
    }

    // ---- residual + LN2 -> x' ----
    {
        float rs = rs_ptr[0];
        float rs1[4] = {0, 0, 0, 0}, rs2[4] = {0, 0, 0, 0};
#pragma unroll
        for (int t = 0; t < 8; ++t) {
            int col = t * 16 + n;
            float bia = b2v[col];
#pragma unroll
            for (int r = 0; r < 4; ++r) {
                int row = wr + q * 4 + r;
                float v = rs * (acc[t][r] + bia) +
                          xresP[(size_t)(rowbase + row) * D_ + col];
                acc[t][r] = v;
                rs1[r] += v;
                rs2[r] += v * v;
            }
        }
#pragma unroll
        for (int mk = 1; mk < 16; mk <<= 1)
#pragma unroll
            for (int r = 0; r < 4; ++r) {
                rs1[r] += __shfl_xor(rs1[r], mk, 64);
                rs2[r] += __shfl_xor(rs2[r], mk, 64);
            }
        float mr[4], rv[4];
#pragma unroll
        for (int r = 0; r < 4; ++r) {
            float mm = rs1[r] * (1.f / 128.f);
            mr[r] = mm;
            rv[r] = rsqrtf(rs2[r] * (1.f / 128.f) - mm * mm + EPS_);
        }
        if constexpr (LAST) {
            int rowid[4];
#pragma unroll
            for (int r = 0; r < 4; ++r) {
                int rl = wr + q * 4 + r;
                rowid[r] = (rl < nrows) ? blist[rowbase + rl] : -1;
            }
#pragma unroll
            for (int t = 0; t < 8; ++t) {
                int col = t * 16 + n;
                float gg = g2v[col], bbv = e2v[col];
#pragma unroll
                for (int r = 0; r < 4; ++r) {
                    if (rowid[r] >= 0) {
                        float nv = (acc[t][r] - mr[r]) * rv[r] * gg + bbv +
                                   x0[(size_t)rowid[r] * D_ + col];
                        OutF[(size_t)rowid[r] * D_ + col] = nv;
                    }
                }
            }
        } else {
#pragma unroll
            for (int t = 0; t < 8; ++t) {
                int col = t * 16 + n;
                float gg = g2v[col], bbv = e2v[col];
#pragma unroll
                for (int r = 0; r < 4; ++r) {
                    int row = wr + q * 4 + r;
                    float nv = (acc[t][r] - mr[r]) * rv[r] * gg + bbv;
                    acc[t][r] = nv;
                    if (row < nrows)
                        OutF[(size_t)(rowbase + row) * D_ + col] = nv;
                }
            }
        }
    }

    if constexpr (!LAST) {
        const unsigned short* Sn = SnAll + (size_t)pp * D_ * D_;
        // transpose x' into own rows
#pragma unroll
        for (int t = 0; t < 8; ++t)
#pragma unroll
            for (int r = 0; r < 4; ++r) {
                int rl = q * 4 + r;
                int c = (t * 16 + n) >> 3;
                sA[(wr + rl) * 128 + ((c ^ rl) << 3) + (n & 7)] = f2bf(acc[t][r]);
            }
        // ---- GEMM3: x' @ Sn ----
#pragma unroll
        for (int t = 0; t < 8; ++t) acc[t] = (f32x4){0.f, 0.f, 0.f, 0.f};
#pragma unroll
        for (int kc = 0; kc < 4; ++kc) {
            int cs = (((kc << 2) + q) ^ n) << 3;
            bf16x8 af = *(const bf16x8*)(sA + (wr + n) * 128 + cs);
            int ko = kc * 32 + q * 8;
#pragma unroll
            for (int t = 0; t < 8; ++t) {
                bf16x8 bv = *(const bf16x8*)(Sn + (t * 16 + n) * 128 + ko);
                acc[t] = __builtin_amdgcn_mfma_f32_16x16x32_bf16(af, bv, acc[t], 0, 0, 0);
            }
        }
        // transpose xt into own rows + wave-local coalesced store
#pragma unroll
        for (int t = 0; t < 8; ++t)
#pragma unroll
            for (int r = 0; r < 4; ++r) {
                int rl = q * 4 + r;
                int c = (t * 16 + n) >> 3;
                sA[(wr + rl) * 128 + ((c ^ rl) << 3) + (n & 7)] = f2bf(acc[t][r]);
            }
        int rl2 = lane >> 2, cb = lane & 3;
        if (rl2 < nrows - wr) {
#pragma unroll
            for (int i = 0; i < 4; ++i) {
                int c = i * 4 + cb;
                uint4 v = *(const uint4*)(sA + (wr + rl2) * 128 + ((c ^ rl2) << 3));
                *(uint4*)(OutXt + (size_t)(rowbase + wr + rl2) * D_ + (c << 3)) = v;
            }
        }
    }
}

// ---------------------------------------------------------------------------
// Host launch
// ---------------------------------------------------------------------------

extern "C" void kernel_launch(void* const* d_in, const int* in_sizes, int n_in,
                              void* d_out, int out_size, void* d_ws, size_t ws_size,
                              hipStream_t stream) {
    const float* x0 = (const float*)d_in[0];
    const int* ei = (const int*)d_in[1];
    const int* ring = (const int*)d_in[2];
    const float* Wr = (const float*)d_in[3];
    const float* S = (const float*)d_in[4];
    const float* dS = (const float*)d_in[5];
    const float* R = (const float*)d_in[6];
    const float* dR = (const float*)d_in[7];
    const float* rsc = (const float*)d_in[8];
    const float* W1 = (const float*)d_in[9];
    const float* b1 = (const float*)d_in[10];
    const float* lng = (const float*)d_in[11];
    const float* lnb = (const float*)d_in[12];
    const float* W2 = (const float*)d_in[13];
    const float* b2 = (const float*)d_in[14];
    const float* ng = (const float*)d_in[15];
    const float* nb = (const float*)d_in[16];
    float* out = (float*)d_out;

    char* w = (char*)d_ws;
    auto alloc = [&](size_t bytes) {
        char* p = w;
        w += (bytes + 15) & ~(size_t)15;
        return p;
    };
    const size_t NP = (size_t)(N_ + 64);  // padded rows (tile-tail overrun + dummy)
    unsigned short* xbP = (unsigned short*)alloc(NP * D_ * 2);    // bf16 x, permuted
    unsigned short* bufAb = (unsigned short*)alloc(NP * D_ * 2);  // xt_p (+zero row N_)
    unsigned short* bufBb = (unsigned short*)alloc(NP * D_ * 2);  // agg_p
    float* xbufP = (float*)alloc(NP * D_ * 4);                    // fp32 x, permuted
    unsigned short* Sb = (unsigned short*)alloc((size_t)L_ * P_ * D_ * D_ * 2);
    unsigned short* Dmb = (unsigned short*)alloc((size_t)L_ * P_ * D_ * D_ * 2);
    unsigned short* W2b = (unsigned short*)alloc((size_t)L_ * D_ * D_ * 2);
    unsigned short* Arh = (unsigned short*)alloc((size_t)MAT * 16384 * 2);
    unsigned short* Arl = (unsigned short*)alloc((size_t)MAT * 16384 * 2);
    unsigned short* W1h = (unsigned short*)alloc((size_t)3 * 16384 * 2);
    unsigned short* W1l = (unsigned short*)alloc((size_t)3 * 16384 * 2);
    unsigned short* Wrth = (unsigned short*)alloc((size_t)3 * 16384 * 2);
    unsigned short* Wrtl = (unsigned short*)alloc((size_t)3 * 16384 * 2);
    unsigned short* T1th = (unsigned short*)alloc((size_t)MAT * 16384 * 2);
    unsigned short* T1tl = (unsigned short*)alloc((size_t)MAT * 16384 * 2);
    float* dnorm = (float*)alloc((size_t)N_ * 4);
    float* dnormp = (float*)alloc(NP * 4);
    int* histG = (int*)alloc((size_t)HTOT * 4);
    unsigned* bufT = (unsigned*)alloc((size_t)E_ * 4);
    unsigned char* bufS8 = (unsigned char*)alloc((size_t)E_);
    unsigned short* eSrc = (unsigned short*)alloc((size_t)E_ * 2);
    int* offT = (int*)alloc((size_t)(N_ + 1) * 4);
    int* pol = (int*)alloc((size_t)N_ * 4);
    int* boff = (int*)alloc((size_t)(P_ + 1) * 4);
    int* tileOff = (int*)alloc((size_t)(P_ + 1) * 4);
    int* blist = (int*)alloc((size_t)N_ * 4);
    int* perm = (int*)alloc((size_t)N_ * 4);
    int* blkSum = (int*)alloc((size_t)NSB * 4);
    int* blkOff = (int*)alloc((size_t)NSB * 4);
    int* bcnt = (int*)alloc((size_t)2 * P_ * 4);  // zeroed region: bcnt + bcur
    int* bcur = bcnt + P_;

    hipMemsetAsync(bcnt, 0, (size_t)2 * P_ * 4, stream);

    const int BTILES = N_ / TM + P_;  // 790, upper bound on bucketed tiles

    setup_nk<<<NBK, 256, 0, stream>>>(ring, pol, bcnt, ei, histG);
    scanH1<<<NSB, 1024, 0, stream>>>(histG, blkSum);
    scanH2<<<1, 64, 0, stream>>>(blkSum, blkOff, offT, bcnt, boff, tileOff);
    scanH3<<<NSB, 1024, 0, stream>>>(histG, blkOff);
    scatterTS<<<NBK, 256, 0, stream>>>(ei, histG, bufT, bufS8);
    finalize3<<<3 * NBUK, 256, 0, stream>>>(bufT, bufS8, histG, offT, eSrc, dnorm,
                                            pol, boff, bcur, blist, perm);
    prep_all<<<GPREP, 256, 0, stream>>>(x0, perm, blist, xbP, xbufP, bufAb,
                                        dnorm, dnormp, eSrc, S, dS, Sb, W2, W2b,
                                        R, dR, W1, Wr, Arh, Arl, W1h, W1l, Wrth, Wrtl);
    small_mfma<false, true, true><<<2 * MAT, 256, 0, stream>>>(
        W1h, W1l, Arh, Arl, T1th, T1tl);
    small_mfma<true, false, false><<<2 * MAT, 256, 0, stream>>>(
        T1th, T1tl, Wrth, Wrtl, Dmb, nullptr);

    // layer 0 send-transform: xt0_p = x_p @ (S+dS)[0][pol]
    gemm_xt0<<<BTILES, 256, 0, stream>>>(xbP, Sb, bufAb, boff, tileOff);

    for (int l = 0; l < L_; ++l) {
        const size_t lPDD = (size_t)l * P_ * D_ * D_;
        const size_t lDD = (size_t)l * D_ * D_;
        const size_t lD = (size_t)l * D_;
        aggregate_bf<<<N_ / 4, 256, 0, stream>>>(bufAb, offT, eSrc, bufBb, perm);
        if (l < L_ - 1) {
            fused_layer<false><<<BTILES, 256, 0, stream>>>(
                bufBb, Dmb + lPDD, W2b + lDD, Sb + lPDD + (size_t)P_ * D_ * D_,
                boff, tileOff, blist, dnormp,
                b1 + lD, lng + lD, lnb + lD, b2 + lD, ng + lD, nb + lD,
                rsc + l, xbufP, nullptr, xbufP, bufAb);
        } else {
            fused_layer<true><<<BTILES, 256, 0, stream>>>(
                bufBb, Dmb + lPDD, W2b + lDD, nullptr,
                boff, tileOff, blist, dnormp,
                b1 + lD, lng + lD, lnb + lD, b2 + lD, ng + lD, nb + lD,
                rsc + l, xbufP, x0, out, nullptr);
        }
    }
}